// Round 7
// baseline (575.311 us; speedup 1.0000x reference)
//
#include <hip/hip_runtime.h>
#include <hip/hip_bf16.h>
#include <stdint.h>

#define S_LEN 2048
#define HSZ 2048
#define NE 8
#define TOPK 2
#define NKVH 16
#define HD 128
#define NQH 32
#define QSZ 2048

typedef __attribute__((ext_vector_type(8))) __bf16 bf16x8;
typedef __attribute__((ext_vector_type(4))) float f32x4;

#define BM 256
#define BN 256
#define BK 64

__device__ __forceinline__ void gload_lds16(const void* g, void* l) {
  __builtin_amdgcn_global_load_lds((__attribute__((address_space(1))) void*)g,
                                   (__attribute__((address_space(3))) void*)l, 16, 0, 0);
}

__device__ __forceinline__ bf16x8 pack8(float4 a, float4 b) {
  bf16x8 r;
  r[0] = (__bf16)a.x; r[1] = (__bf16)a.y; r[2] = (__bf16)a.z; r[3] = (__bf16)a.w;
  r[4] = (__bf16)b.x; r[5] = (__bf16)b.y; r[6] = (__bf16)b.z; r[7] = (__bf16)b.w;
  return r;
}

// ---------------- cast f32 -> bf16 (hidden states only) ----------------
__global__ __launch_bounds__(256) void cast_kernel(const float* __restrict__ src,
                                                   __bf16* __restrict__ dst, long n) {
  long i0 = ((long)blockIdx.x * 256 + threadIdx.x) * 4;
  long stride = (long)gridDim.x * 256 * 4;
  for (long i = i0; i < n; i += stride) {
    float4 v = *(const float4*)(src + i);
    unsigned short a = __builtin_bit_cast(unsigned short, (__bf16)v.x);
    unsigned short b = __builtin_bit_cast(unsigned short, (__bf16)v.y);
    unsigned short c = __builtin_bit_cast(unsigned short, (__bf16)v.z);
    unsigned short d = __builtin_bit_cast(unsigned short, (__bf16)v.w);
    uint2 o;
    o.x = (unsigned)a | ((unsigned)b << 16);
    o.y = (unsigned)c | ((unsigned)d << 16);
    *(uint2*)(dst + i) = o;
  }
}

// ---------------- router: logits + top2 + gates ----------------
__global__ __launch_bounds__(256) void router_kernel(const float* __restrict__ hs,
                                                     const float* __restrict__ rw,
                                                     int* __restrict__ sel,
                                                     float* __restrict__ gates) {
  const int s = blockIdx.x * 4 + (threadIdx.x >> 6);
  const int lane = threadIdx.x & 63;
  const float* row = hs + (size_t)s * HSZ;
  float acc[NE];
#pragma unroll
  for (int e = 0; e < NE; ++e) acc[e] = 0.f;
  for (int j = lane; j < HSZ; j += 64) {
    float x = row[j];
#pragma unroll
    for (int e = 0; e < NE; ++e) acc[e] += x * rw[e * HSZ + j];
  }
#pragma unroll
  for (int e = 0; e < NE; ++e) {
#pragma unroll
    for (int off = 32; off > 0; off >>= 1) acc[e] += __shfl_xor(acc[e], off);
  }
  if (lane == 0) {
    int i0 = 0; float v0 = acc[0];
#pragma unroll
    for (int e = 1; e < NE; ++e) if (acc[e] > v0) { v0 = acc[e]; i0 = e; }
    int i1 = -1; float v1 = -1e30f;
#pragma unroll
    for (int e = 0; e < NE; ++e) if (e != i0 && acc[e] > v1) { v1 = acc[e]; i1 = e; }
    float ge = __expf(v1 - v0);
    float den = 1.f + ge;
    sel[s * 2] = i0; sel[s * 2 + 1] = i1;
    gates[s * 2] = 1.f / den; gates[s * 2 + 1] = ge / den;
  }
}

// ---------------- bucket (token,slot) pairs by expert ----------------
__global__ void bucket_kernel(const int* __restrict__ sel, int* __restrict__ pair_list,
                              int* __restrict__ expert_off) {
  __shared__ int cnt[NE], base[NE];
  const int t = threadIdx.x;
  if (t < NE) cnt[t] = 0;
  __syncthreads();
  for (int p2 = t; p2 < S_LEN * TOPK; p2 += 256) atomicAdd(&cnt[sel[p2]], 1);
  __syncthreads();
  if (t == 0) {
    int run = 0;
#pragma unroll
    for (int e = 0; e < NE; ++e) { base[e] = run; expert_off[e] = run; run += cnt[e]; }
    expert_off[NE] = run;
  }
  __syncthreads();
  for (int p2 = t; p2 < S_LEN * TOPK; p2 += 256) {
    int pos = atomicAdd(&base[sel[p2]], 1);
    pair_list[pos] = p2;
  }
}

// ---------------- GEMM v5: 256x256 tile, 8 waves, dbuf, race-free schedule ----
// Per iter: pack B(ti) (implicit vmcnt drains B(ti) AND the older A(ti)) ->
// lgkmcnt(0) + s_barrier (per-wave loads complete BEFORE barrier -> cross-wave
// safe) -> issue A(ti+1) gload_lds + B(ti+1) f32 loads -> MFMA(ti).
// Issued bytes halve vs 128^2: A panels re-read 8x (not 16x), B 2x (not 4x).
template <int MODE>
__global__ __launch_bounds__(512, 1) void gemm_kernel(const __bf16* __restrict__ A_src,
                                                      const float* __restrict__ B_src,
                                                      const int* __restrict__ pair_list,
                                                      const int* __restrict__ expert_off,
                                                      const float* __restrict__ gates,
                                                      __bf16* __restrict__ out_bf,
                                                      __bf16* __restrict__ out_vT,
                                                      float* __restrict__ out_f32) {
  constexpr int KD = 2048;
  constexpr int NT = KD / BK;  // 32
  const int n0 = blockIdx.x * BN;
  const int m0 = blockIdx.y * BM;
  const int e = blockIdx.z;
  int start = 0, cntv = S_LEN;
  if constexpr (MODE != 0) {
    start = expert_off[e];
    cntv = expert_off[e + 1] - start;
    if (m0 >= cntv) return;
  }
  const float* Bb = B_src + (size_t)e * QSZ * HSZ;
  __shared__ __attribute__((aligned(16))) __bf16 As[2][BM * BK];  // 2x32KB
  __shared__ __attribute__((aligned(16))) __bf16 Bs[2][BN * BK];  // 2x32KB
  __shared__ const __bf16* a_rows[BM];
  __shared__ int row_pair[BM];
  const int t = threadIdx.x;
  if (t < BM) {
    if constexpr (MODE == 0) {
      a_rows[t] = A_src + (size_t)(m0 + t) * KD;
      row_pair[t] = 0;
    } else {
      int idx = m0 + t;
      bool valid = idx < cntv;
      int pp = pair_list[start + (valid ? idx : 0)];
      row_pair[t] = valid ? pp : -1;
      size_t arow = (MODE == 1) ? (size_t)(pp >> 1) : (size_t)pp;
      a_rows[t] = A_src + arow * (size_t)KD;
    }
  }
  __syncthreads();

  const int lane = t & 63, w = t >> 6;
  const int wr = (w >> 2) * 128, wc = (w & 3) * 64;  // 2M x 4N waves
  const int lr = lane & 15, g = lane >> 4;
  const int xa = lr & 7;  // read-side swizzle key

  // A staging: 2048 16B-chunks, 4/thread; linear LDS dest, inverse-swizzled src.
  const __bf16* a_srow[4];
  int a_soff[4];
#pragma unroll
  for (int i = 0; i < 4; ++i) {
    const int c = t + i * 512;
    const int row = c >> 3, win = c & 7;
    a_srow[i] = a_rows[row];
    a_soff[i] = (win ^ (row & 7)) * 8;
  }

  // B staging: thread t -> row t>>1, f32 elems [(t&1)*32, +32); swizzled ds_write.
  const int brow = t >> 1;
  const int bh = t & 1;
  const float* bp = Bb + (size_t)(n0 + brow) * KD + bh * 32;
  int bo[4];
#pragma unroll
  for (int j = 0; j < 4; ++j) bo[j] = brow * BK + (((bh * 4 + j) ^ (brow & 7)) * 8);

  f32x4 acc[8][4];
#pragma unroll
  for (int m = 0; m < 8; ++m)
#pragma unroll
    for (int n = 0; n < 4; ++n) acc[m][n] = (f32x4)0.f;

  auto stageA = [&](int dstbuf, int k0) {
#pragma unroll
    for (int i = 0; i < 4; ++i)
      gload_lds16(a_srow[i] + k0 + a_soff[i], (char*)As[dstbuf] + (t + i * 512) * 16);
  };

  float4 c0, c1, c2, c3, c4, c5, c6, c7;
#define B_LOAD(KB)                                                            \
  c0 = *(const float4*)(bp + (KB));      c1 = *(const float4*)(bp + (KB) + 4);  \
  c2 = *(const float4*)(bp + (KB) + 8);  c3 = *(const float4*)(bp + (KB) + 12); \
  c4 = *(const float4*)(bp + (KB) + 16); c5 = *(const float4*)(bp + (KB) + 20); \
  c6 = *(const float4*)(bp + (KB) + 24); c7 = *(const float4*)(bp + (KB) + 28);

  // prologue: A(0) first, then B(0) — pack(0)'s wait on B implies A done.
  stageA(0, 0);
  B_LOAD(0)
  __builtin_amdgcn_sched_barrier(0);

#pragma unroll 2
  for (int ti = 0; ti < NT; ++ti) {
    const int cur = ti & 1;
    // pack + swizzled ds_write of B(ti); implicit vmcnt drains B(ti) (and A(ti))
    *(bf16x8*)(&Bs[cur][bo[0]]) = pack8(c0, c1);
    *(bf16x8*)(&Bs[cur][bo[1]]) = pack8(c2, c3);
    *(bf16x8*)(&Bs[cur][bo[2]]) = pack8(c4, c5);
    *(bf16x8*)(&Bs[cur][bo[3]]) = pack8(c6, c7);
    asm volatile("s_waitcnt lgkmcnt(0)" ::: "memory");
    __builtin_amdgcn_s_barrier();  // tile ti fully resident for ALL waves

    if (ti + 1 < NT) {  // issue next tile under compute
      stageA(cur ^ 1, (ti + 1) * BK);
      B_LOAD((ti + 1) * BK)
    }
    __builtin_amdgcn_sched_barrier(0);

#pragma unroll
    for (int kk = 0; kk < BK; kk += 32) {
      bf16x8 af[8], bfv[4];
#pragma unroll
      for (int m = 0; m < 8; ++m)
        af[m] = *(const bf16x8*)(&As[cur][(wr + m * 16 + lr) * BK + (((kk >> 3) + g) ^ xa) * 8]);
#pragma unroll
      for (int n = 0; n < 4; ++n)
        bfv[n] = *(const bf16x8*)(&Bs[cur][(wc + n * 16 + lr) * BK + (((kk >> 3) + g) ^ xa) * 8]);
#pragma unroll
      for (int m = 0; m < 8; ++m)
#pragma unroll
        for (int n = 0; n < 4; ++n)
          acc[m][n] = __builtin_amdgcn_mfma_f32_16x16x32_bf16(af[m], bfv[n], acc[m][n], 0, 0, 0);
    }
    __builtin_amdgcn_sched_barrier(0);  // keep next iter's pack below this compute
  }
#undef B_LOAD

  if constexpr (MODE == 0) {
    if (n0 < 2048) {
#pragma unroll
      for (int m = 0; m < 8; ++m)
#pragma unroll
        for (int r = 0; r < 4; ++r) {
          const int row = wr + m * 16 + g * 4 + r;
#pragma unroll
          for (int n = 0; n < 4; ++n) {
            const int col = n0 + wc + n * 16 + lr;
            out_bf[(size_t)(m0 + row) * 2048 + col] = (__bf16)acc[m][n][r];
          }
        }
    } else {
      // V half: write transposed [d_global = col-2048][s], 4 consecutive s packed
#pragma unroll
      for (int m = 0; m < 8; ++m) {
        const int sb = m0 + wr + m * 16 + g * 4;
#pragma unroll
        for (int n = 0; n < 4; ++n) {
          const int cv = n0 + wc + n * 16 + lr - 2048;
          uint2 pk;
          unsigned short h0 = __builtin_bit_cast(unsigned short, (__bf16)acc[m][n][0]);
          unsigned short h1 = __builtin_bit_cast(unsigned short, (__bf16)acc[m][n][1]);
          unsigned short h2 = __builtin_bit_cast(unsigned short, (__bf16)acc[m][n][2]);
          unsigned short h3 = __builtin_bit_cast(unsigned short, (__bf16)acc[m][n][3]);
          pk.x = (unsigned)h0 | ((unsigned)h1 << 16);
          pk.y = (unsigned)h2 | ((unsigned)h3 << 16);
          *(uint2*)(out_vT + (size_t)cv * S_LEN + sb) = pk;
        }
      }
    }
  } else {
#pragma unroll
    for (int m = 0; m < 8; ++m) {
#pragma unroll
      for (int r = 0; r < 4; ++r) {
        const int row = wr + m * 16 + g * 4 + r;
        const int pp = row_pair[row];
        if (pp < 0) continue;
        if constexpr (MODE == 1) {
#pragma unroll
          for (int n = 0; n < 4; ++n) {
            const int col = n0 + wc + n * 16 + lr;
            out_bf[(size_t)pp * QSZ + col] = (__bf16)acc[m][n][r];
          }
        } else {
          const float gt = gates[pp];
#pragma unroll
          for (int n = 0; n < 4; ++n) {
            const int col = n0 + wc + n * 16 + lr;
            out_f32[(size_t)pp * HSZ + col] = acc[m][n][r] * gt;
          }
        }
      }
    }
  }
}

// ---------------- RoPE + layout rearrange ----------------
__global__ __launch_bounds__(256) void rope_q_kernel(const __bf16* __restrict__ q_lin,
                                                     const float* __restrict__ cosb,
                                                     const float* __restrict__ sinb,
                                                     __bf16* __restrict__ q_attn) {
  const int idx = blockIdx.x * 4 + (threadIdx.x >> 6);
  const int lane = threadIdx.x & 63;
  const int s = idx >> 5;
  const int h = idx & 31;
  const int kvh = h >> 1, k = h & 1;
  const __bf16* src = q_lin + ((size_t)s * 2 + k) * QSZ + kvh * HD;
  float x1 = (float)src[lane];
  float x2 = (float)src[lane + 64];
  float c = cosb[s * 64 + lane], sn = sinb[s * 64 + lane];
  __bf16* dst = q_attn + ((size_t)h * S_LEN + s) * HD;
  dst[lane] = (__bf16)(x1 * c - x2 * sn);
  dst[lane + 64] = (__bf16)(x1 * sn + x2 * c);
}

__global__ __launch_bounds__(256) void rope_k_kernel(const __bf16* __restrict__ kv_lin,
                                                     const float* __restrict__ cosb,
                                                     const float* __restrict__ sinb,
                                                     __bf16* __restrict__ k_attn) {
  const int idx = blockIdx.x * 4 + (threadIdx.x >> 6);
  const int lane = threadIdx.x & 63;
  const int s = idx >> 4;
  const int gq = idx & 15;
  const __bf16* ksrc = kv_lin + (size_t)s * 2048 + gq * HD;
  float x1 = (float)ksrc[lane], x2 = (float)ksrc[lane + 64];
  float c = cosb[s * 64 + lane], sn = sinb[s * 64 + lane];
  __bf16* kd = k_attn + ((size_t)gq * S_LEN + s) * HD;
  kd[lane] = (__bf16)(x1 * c - x2 * sn);
  kd[lane + 64] = (__bf16)(x1 * sn + x2 * c);
}

// ---------------- flash attention v2 (causal, GQA 2:1) ----------------
__global__ __launch_bounds__(256, 2) void attn_kernel(const __bf16* __restrict__ q_attn,
                                                      const __bf16* __restrict__ k_attn,
                                                      const __bf16* __restrict__ vT,
                                                      __bf16* __restrict__ attn4) {
  __shared__ __attribute__((aligned(16))) __bf16 Ks[2][64 * 128];
  __shared__ __attribute__((aligned(16))) __bf16 Vs[2][128 * 64];
  const int h = blockIdx.x;
  const int by = (blockIdx.y < 8) ? blockIdx.y : 23 - blockIdx.y;  // pair heavy+light per CU
  const int s0 = by * 128;
  const int t = threadIdx.x;
  const int lane = t & 63;
  const int w = t >> 6;
  const int g = lane >> 4;
  const int lr = lane & 15;
  const int kvh = h >> 1;

  int koff[4], voff[4];
#pragma unroll
  for (int i = 0; i < 4; ++i) {
    const int c = t + i * 256;
    const int kvL = c >> 4, w16 = c & 15;
    koff[i] = kvL * HD + ((w16 ^ (kvL & 7)) * 8);
    const int d = c >> 3, w8 = c & 7;
    voff[i] = d * S_LEN + ((w8 ^ (d & 7)) * 8);
  }
  const __bf16* Kb = k_attn + (size_t)kvh * S_LEN * HD;
  const __bf16* Vb = vT + (size_t)kvh * HD * S_LEN;

  auto stage = [&](int buf, int kv0) {
#pragma unroll
    for (int i = 0; i < 4; ++i) {
      const int c = t + i * 256;
      gload_lds16(Kb + (size_t)kv0 * HD + koff[i], (char*)Ks[buf] + c * 16);
      gload_lds16(Vb + (size_t)kv0 + voff[i], (char*)Vs[buf] + c * 16);
    }
  };

  bf16x8 qf[2][4];
#pragma unroll
  for (int m = 0; m < 2; ++m) {
    const __bf16* qbase = q_attn + ((size_t)h * S_LEN + s0 + w * 32 + m * 16 + lr) * HD;
#pragma unroll
    for (int ds = 0; ds < 4; ++ds) qf[m][ds] = *(const bf16x8*)(qbase + ds * 32 + g * 8);
  }

  float m_run[2] = {-1e30f, -1e30f}, l_run[2] = {0.f, 0.f};
  f32x4 acc[2][8];
#pragma unroll
  for (int m = 0; m < 2; ++m)
#pragma unroll
    for (int dt = 0; dt < 8; ++dt) acc[m][dt] = (f32x4)0.f;

  const int xr = (lr & 7) << 4;
  const int nt = 2 * by + 2;
  stage(0, 0);
  for (int ti = 0; ti < nt; ++ti) {
    const int cur = ti & 1;
    const int kv0 = ti * 64;
    __syncthreads();
    if (ti + 1 < nt) stage(cur ^ 1, kv0 + 64);

    f32x4 sc[2][4];
#pragma unroll
    for (int m = 0; m < 2; ++m)
#pragma unroll
      for (int b = 0; b < 4; ++b) sc[m][b] = (f32x4)0.f;
#pragma unroll
    for (int b = 0; b < 4; ++b) {
#pragma unroll
      for (int ds = 0; ds < 4; ++ds) {
        const bf16x8 kf = *(const bf16x8*)((const char*)Ks[cur] +
            (b * 16 + lr) * 256 + ((ds * 64 + g * 16) ^ xr));
        sc[0][b] = __builtin_amdgcn_mfma_f32_16x16x32_bf16(kf, qf[0][ds], sc[0][b], 0, 0, 0);
        sc[1][b] = __builtin_amdgcn_mfma_f32_16x16x32_bf16(kf, qf[1][ds], sc[1][b], 0, 0, 0);
      }
    }

    bf16x8 paf[2][2];
#pragma unroll
    for (int m = 0; m < 2; ++m) {
      const int qrow = s0 + w * 32 + m * 16 + lr;
      float p[4][4];
      float tmax = -1e30f;
#pragma unroll
      for (int b = 0; b < 4; ++b)
#pragma unroll
        for (int r = 0; r < 4; ++r) {
          const int kv = kv0 + b * 16 + g * 4 + r;
          float v = sc[m][b][r] * 0.08838834764831845f;
          if (kv > qrow) v = -1e30f;
          p[b][r] = v;
          tmax = fmaxf(tmax, v);
        }
      tmax = fmaxf(tmax, __shfl_xor(tmax, 16));
      tmax = fmaxf(tmax, __shfl_xor(tmax, 32));
      const float m_new = fmaxf(m_run[m], tmax);
      const float alpha = __expf(m_run[m] - m_new);
      float lsum = 0.f;
#pragma unroll
      for (int b = 0; b < 4; ++b)
#pragma unroll
        for (int r = 0; r < 4; ++r) {
          p[b][r] = __expf(p[b][r] - m_new);
          lsum += p[b][r];
        }
      lsum += __shfl_xor(lsum, 16);
      lsum += __shfl_xor(lsum, 32);
      l_run[m] = l_run[m] * alpha + lsum;
      m_run[m] = m_new;

      float ar[4];
#pragma unroll
      for (int r = 0; r < 4; ++r) ar[r] = __shfl(alpha, g * 4 + r);
#pragma unroll
      for (int dt = 0; dt < 8; ++dt)
#pragma unroll
        for (int r = 0; r < 4; ++r) acc[m][dt][r] *= ar[r];

#pragma unroll
      for (int half = 0; half < 2; ++half) {
        bf16x8 af;
#pragma unroll
        for (int j = 0; j < 8; ++j) {
          const int srcl = lr + 16 * ((g & 1) * 2 + (j >> 2));
          const float va = __shfl(p[half * 2][j & 3], srcl);
          const float vb = __shfl(p[half * 2 + 1][j & 3], srcl);
          af[j] = (__bf16)((g >> 1) ? vb : va);
        }
        paf[m][half] = af;
      }
    }

#pragma unroll
    for (int dt = 0; dt < 8; ++dt) {
      const char* vrow = (const char*)Vs[cur] + (dt * 16 + lr) * 128;
      const bf16x8 v0 = *(const bf16x8*)(vrow + ((g * 16) ^ xr));
      const bf16x8 v1 = *(const bf16x8*)(vrow + ((64 + g * 16) ^ xr));
      acc[0][dt] = __builtin_amdgcn_mfma_f32_16x16x32_bf16(paf[0][0], v0, acc[0][dt], 0, 0, 0);
      acc[0][dt] = __builtin_amdgcn_mfma_f32_16x16x32_bf16(paf[0][1], v1, acc[0][dt], 0, 0, 0);
      acc[1][dt] = __builtin_amdgcn_mfma_f32_16x16x32_bf16(paf[1][0], v0, acc[1][dt], 0, 0, 0);
      acc[1][dt] = __builtin_amdgcn_mfma_f32_16x16x32_bf16(paf[1][1], v1, acc[1][dt], 0, 0, 0);
    }
  }

#pragma unroll
  for (int m = 0; m < 2; ++m) {
    const float li = 1.f / l_run[m];
    float linv[4];
#pragma unroll
    for (int r = 0; r < 4; ++r) linv[r] = __shfl(li, g * 4 + r);
#pragma unroll
    for (int dt = 0; dt < 8; ++dt)
#pragma unroll
      for (int r = 0; r < 4; ++r) {
        const int qg = s0 + w * 32 + m * 16 + g * 4 + r;
        attn4[((size_t)qg * 2 + (h & 1)) * QSZ + kvh * HD + dt * 16 + lr] =
            (__bf16)(acc[m][dt][r] * linv[r]);
      }
  }
}

// ---------------- final: out = bias + o_tmp[2s] + o_tmp[2s+1] ----------------
__global__ __launch_bounds__(256) void final_kernel(const float* __restrict__ o_tmp,
                                                    const float* __restrict__ bias,
                                                    float* __restrict__ out) {
  const size_t i = ((size_t)blockIdx.x * 256 + threadIdx.x) * 4;
  const int s = (int)(i >> 11);
  const int hcol = (int)(i & 2047);
  float4 a = *(const float4*)(o_tmp + ((size_t)s * 2) * HSZ + hcol);
  float4 b = *(const float4*)(o_tmp + ((size_t)s * 2 + 1) * HSZ + hcol);
  float4 bb = *(const float4*)(bias + hcol);
  float4 o;
  o.x = a.x + b.x + bb.x; o.y = a.y + b.y + bb.y;
  o.z = a.z + b.z + bb.z; o.w = a.w + b.w + bb.w;
  *(float4*)(out + i) = o;
}

extern "C" void kernel_launch(void* const* d_in, const int* in_sizes, int n_in,
                              void* d_out, int out_size, void* d_ws, size_t ws_size,
                              hipStream_t stream) {
  (void)in_sizes; (void)n_in; (void)out_size; (void)ws_size;
  const float* hs = (const float*)d_in[0];
  const float* cosb = (const float*)d_in[2];
  const float* sinb = (const float*)d_in[3];
  const float* rw = (const float*)d_in[4];
  const float* qw = (const float*)d_in[5];
  const float* ow = (const float*)d_in[6];
  const float* kvw = (const float*)d_in[7];
  const float* bias = (const float*)d_in[8];
  float* outp = (float*)d_out;

  char* base = (char*)d_ws;
  size_t off = 0;
  auto take = [&](size_t bytes) {
    char* r = base + off;
    off += (bytes + 255) & ~(size_t)255;
    return r;
  };
  __bf16* hid_bf  = (__bf16*)take((size_t)S_LEN * HSZ * 2);          // 8 MB
  __bf16* k_attn  = (__bf16*)take((size_t)NKVH * S_LEN * HD * 2);    // 8 MB
  __bf16* v_attnT = (__bf16*)take((size_t)NKVH * HD * S_LEN * 2);    // 8 MB, [d_global][s]
  char* bufA = take((size_t)S_LEN * 4096 * 2);                        // 16 MB: kv_lin(K), then attn4
  char* bufBC = take((size_t)S_LEN * TOPK * HSZ * 4);                 // 32 MB: q_lin|q_attn, then o_tmp
  int* sel = (int*)take((size_t)S_LEN * TOPK * 4);
  float* gates = (float*)take((size_t)S_LEN * TOPK * 4);
  int* pair_list = (int*)take((size_t)S_LEN * TOPK * 4);
  int* expert_off = (int*)take((size_t)(NE + 1) * 4);

  __bf16* kv_lin = (__bf16*)bufA;
  __bf16* attn4 = (__bf16*)bufA;
  __bf16* q_lin = (__bf16*)bufBC;
  __bf16* q_attn = (__bf16*)(bufBC + (size_t)16 * 1024 * 1024);
  float* o_tmp = (float*)bufBC;

  cast_kernel<<<1024, 256, 0, stream>>>(hs, hid_bf, (long)S_LEN * HSZ);
  router_kernel<<<S_LEN / 4, 256, 0, stream>>>(hs, rw, sel, gates);
  bucket_kernel<<<1, 256, 0, stream>>>(sel, pair_list, expert_off);
  gemm_kernel<0><<<dim3(4096 / BN, S_LEN / BM, 1), 512, 0, stream>>>(
      hid_bf, kvw, nullptr, nullptr, nullptr, kv_lin, v_attnT, nullptr);
  rope_k_kernel<<<S_LEN * NKVH / 4, 256, 0, stream>>>(kv_lin, cosb, sinb, k_attn);
  gemm_kernel<1><<<dim3(QSZ / BN, 8, NE), 512, 0, stream>>>(
      hid_bf, qw, pair_list, expert_off, nullptr, q_lin, nullptr, nullptr);
  rope_q_kernel<<<S_LEN * NQH / 4, 256, 0, stream>>>(q_lin, cosb, sinb, q_attn);
  attn_kernel<<<dim3(NQH, 16), 256, 0, stream>>>(q_attn, k_attn, v_attnT, attn4);
  gemm_kernel<2><<<dim3(HSZ / BN, 8, NE), 512, 0, stream>>>(
      attn4, ow, pair_list, expert_off, gates, nullptr, nullptr, o_tmp);
  final_kernel<<<(S_LEN * HSZ / 4) / 256, 256, 0, stream>>>(o_tmp, bias, outp);
}

// Round 8
// 425.694 us; speedup vs baseline: 1.3515x; 1.3515x over previous
//
#include <hip/hip_runtime.h>
#include <hip/hip_bf16.h>
#include <stdint.h>

#define S_LEN 2048
#define HSZ 2048
#define NE 8
#define TOPK 2
#define NKVH 16
#define HD 128
#define NQH 32
#define QSZ 2048

typedef __attribute__((ext_vector_type(8))) __bf16 bf16x8;
typedef __attribute__((ext_vector_type(4))) float f32x4;

#define BM 128
#define BN 128
#define BK 64

__device__ __forceinline__ void gload_lds16(const void* g, void* l) {
  __builtin_amdgcn_global_load_lds((__attribute__((address_space(1))) void*)g,
                                   (__attribute__((address_space(3))) void*)l, 16, 0, 0);
}

__device__ __forceinline__ bf16x8 pack8(float4 a, float4 b) {
  bf16x8 r;
  r[0] = (__bf16)a.x; r[1] = (__bf16)a.y; r[2] = (__bf16)a.z; r[3] = (__bf16)a.w;
  r[4] = (__bf16)b.x; r[5] = (__bf16)b.y; r[6] = (__bf16)b.z; r[7] = (__bf16)b.w;
  return r;
}

// ---------------- cast f32 -> bf16 (hidden states only) ----------------
__global__ __launch_bounds__(256) void cast_kernel(const float* __restrict__ src,
                                                   __bf16* __restrict__ dst, long n) {
  long i0 = ((long)blockIdx.x * 256 + threadIdx.x) * 4;
  long stride = (long)gridDim.x * 256 * 4;
  for (long i = i0; i < n; i += stride) {
    float4 v = *(const float4*)(src + i);
    unsigned short a = __builtin_bit_cast(unsigned short, (__bf16)v.x);
    unsigned short b = __builtin_bit_cast(unsigned short, (__bf16)v.y);
    unsigned short c = __builtin_bit_cast(unsigned short, (__bf16)v.z);
    unsigned short d = __builtin_bit_cast(unsigned short, (__bf16)v.w);
    uint2 o;
    o.x = (unsigned)a | ((unsigned)b << 16);
    o.y = (unsigned)c | ((unsigned)d << 16);
    *(uint2*)(dst + i) = o;
  }
}

// ---------------- router: logits + top2 + gates ----------------
__global__ __launch_bounds__(256) void router_kernel(const float* __restrict__ hs,
                                                     const float* __restrict__ rw,
                                                     int* __restrict__ sel,
                                                     float* __restrict__ gates) {
  const int s = blockIdx.x * 4 + (threadIdx.x >> 6);
  const int lane = threadIdx.x & 63;
  const float* row = hs + (size_t)s * HSZ;
  float acc[NE];
#pragma unroll
  for (int e = 0; e < NE; ++e) acc[e] = 0.f;
  for (int j = lane; j < HSZ; j += 64) {
    float x = row[j];
#pragma unroll
    for (int e = 0; e < NE; ++e) acc[e] += x * rw[e * HSZ + j];
  }
#pragma unroll
  for (int e = 0; e < NE; ++e) {
#pragma unroll
    for (int off = 32; off > 0; off >>= 1) acc[e] += __shfl_xor(acc[e], off);
  }
  if (lane == 0) {
    int i0 = 0; float v0 = acc[0];
#pragma unroll
    for (int e = 1; e < NE; ++e) if (acc[e] > v0) { v0 = acc[e]; i0 = e; }
    int i1 = -1; float v1 = -1e30f;
#pragma unroll
    for (int e = 0; e < NE; ++e) if (e != i0 && acc[e] > v1) { v1 = acc[e]; i1 = e; }
    float ge = __expf(v1 - v0);
    float den = 1.f + ge;
    sel[s * 2] = i0; sel[s * 2 + 1] = i1;
    gates[s * 2] = 1.f / den; gates[s * 2 + 1] = ge / den;
  }
}

// ---------------- bucket (token,slot) pairs by expert ----------------
__global__ void bucket_kernel(const int* __restrict__ sel, int* __restrict__ pair_list,
                              int* __restrict__ expert_off) {
  __shared__ int cnt[NE], base[NE];
  const int t = threadIdx.x;
  if (t < NE) cnt[t] = 0;
  __syncthreads();
  for (int p2 = t; p2 < S_LEN * TOPK; p2 += 256) atomicAdd(&cnt[sel[p2]], 1);
  __syncthreads();
  if (t == 0) {
    int run = 0;
#pragma unroll
    for (int e = 0; e < NE; ++e) { base[e] = run; expert_off[e] = run; run += cnt[e]; }
    expert_off[NE] = run;
  }
  __syncthreads();
  for (int p2 = t; p2 < S_LEN * TOPK; p2 += 256) {
    int pos = atomicAdd(&base[sel[p2]], 1);
    pair_list[pos] = p2;
  }
}

// ---------------- GEMM v6: 128^2, distance-2 B pipeline, waits BEFORE barrier -
// iter ti: pack B(ti) [auto-wait regs] -> lgkmcnt(0) -> vmcnt(8) [own A(ti)
// done; B(ti+1) x8 stays in flight] -> s_barrier [tile ti resident for all
// waves, race-free] -> issue A(ti+1) gload_lds -> issue B(ti+2) f32 loads ->
// 32 MFMA. B issue-to-use = 2 iters (covers HBM latency); A = 1 iter (L2-hot).
template <int MODE>
__global__ __launch_bounds__(256, 2) void gemm_kernel(const __bf16* __restrict__ A_src,
                                                      const float* __restrict__ B_src,
                                                      const int* __restrict__ pair_list,
                                                      const int* __restrict__ expert_off,
                                                      const float* __restrict__ gates,
                                                      __bf16* __restrict__ out_bf,
                                                      __bf16* __restrict__ out_vT,
                                                      float* __restrict__ out_f32) {
  constexpr int KD = 2048;
  constexpr int NT = KD / BK;  // 32 (even)
  const int n0 = blockIdx.x * BN;
  const int m0 = blockIdx.y * BM;
  const int e = blockIdx.z;
  int start = 0, cntv = S_LEN;
  if constexpr (MODE != 0) {
    start = expert_off[e];
    cntv = expert_off[e + 1] - start;
    if (m0 >= cntv) return;
  }
  const float* Bb = B_src + (size_t)e * QSZ * HSZ;
  __shared__ __attribute__((aligned(16))) __bf16 As[2][BM * BK];
  __shared__ __attribute__((aligned(16))) __bf16 Bs[2][BN * BK];
  __shared__ const __bf16* a_rows[BM];
  __shared__ int row_pair[BM];
  const int t = threadIdx.x;
  if (t < BM) {
    if constexpr (MODE == 0) {
      a_rows[t] = A_src + (size_t)(m0 + t) * KD;
      row_pair[t] = 0;
    } else {
      int idx = m0 + t;
      bool valid = idx < cntv;
      int pp = pair_list[start + (valid ? idx : 0)];
      row_pair[t] = valid ? pp : -1;
      size_t arow = (MODE == 1) ? (size_t)(pp >> 1) : (size_t)pp;
      a_rows[t] = A_src + arow * (size_t)KD;
    }
  }
  __syncthreads();

  const int lane = t & 63, w = t >> 6;
  const int wr = (w >> 1) * 64, wc = (w & 1) * 64;
  const int lr = lane & 15, g = lane >> 4;
  const int xa = lr & 7;  // read-side swizzle key

  // A staging: 1024 16B-chunks, 4/thread; linear LDS dest, inverse-swizzled src.
  const __bf16* a_srow[4];
  int a_soff[4];
#pragma unroll
  for (int i = 0; i < 4; ++i) {
    const int c = t + i * 256;
    const int row = c >> 3, win = c & 7;
    a_srow[i] = a_rows[row];
    a_soff[i] = (win ^ (row & 7)) * 8;
  }

  // B staging: thread t -> rows {brow, brow+64}, elems [bq*16,+16); swizzled ds_write.
  const int brow = t >> 2;
  const int bq = t & 3;
  const float* bp0 = Bb + (size_t)(n0 + brow) * KD + bq * 16;
  const float* bp1 = bp0 + (size_t)64 * KD;
  const int c0 = (2 * bq) ^ (brow & 7);
  const int c1 = (2 * bq + 1) ^ (brow & 7);
  const int bo00 = brow * BK + c0 * 8, bo01 = brow * BK + c1 * 8;
  const int bo10 = (brow + 64) * BK + c0 * 8, bo11 = (brow + 64) * BK + c1 * 8;

  f32x4 acc[4][4];
#pragma unroll
  for (int m = 0; m < 4; ++m)
#pragma unroll
    for (int n = 0; n < 4; ++n) acc[m][n] = (f32x4)0.f;

  auto stageA = [&](int dstbuf, int k0) {
#pragma unroll
    for (int i = 0; i < 4; ++i)
      gload_lds16(a_srow[i] + k0 + a_soff[i], (char*)As[dstbuf] + (t + i * 256) * 16);
  };
  auto mfma_tile = [&](int cur) {
#pragma unroll
    for (int kk = 0; kk < BK; kk += 32) {
      bf16x8 af[4], bfv[4];
#pragma unroll
      for (int m = 0; m < 4; ++m)
        af[m] = *(const bf16x8*)(&As[cur][(wr + m * 16 + lr) * BK + (((kk >> 3) + g) ^ xa) * 8]);
#pragma unroll
      for (int n = 0; n < 4; ++n)
        bfv[n] = *(const bf16x8*)(&Bs[cur][(wc + n * 16 + lr) * BK + (((kk >> 3) + g) ^ xa) * 8]);
#pragma unroll
      for (int m = 0; m < 4; ++m)
#pragma unroll
        for (int n = 0; n < 4; ++n)
          acc[m][n] = __builtin_amdgcn_mfma_f32_16x16x32_bf16(af[m], bfv[n], acc[m][n], 0, 0, 0);
    }
  };

#define B_LOAD8(S0, S1, S2, S3, S4, S5, S6, S7, KB)                               \
  S0 = *(const float4*)(bp0 + (KB));      S1 = *(const float4*)(bp0 + (KB) + 4);  \
  S2 = *(const float4*)(bp0 + (KB) + 8);  S3 = *(const float4*)(bp0 + (KB) + 12); \
  S4 = *(const float4*)(bp1 + (KB));      S5 = *(const float4*)(bp1 + (KB) + 4);  \
  S6 = *(const float4*)(bp1 + (KB) + 8);  S7 = *(const float4*)(bp1 + (KB) + 12);

// iter: pack -> lgkm -> vmcnt(8) -> barrier -> stageA(ti+1) -> B_LOAD(ti+2) -> MFMA
#define GEMM_STEP(TI, CUR, S0, S1, S2, S3, S4, S5, S6, S7)                   \
  *(bf16x8*)(&Bs[CUR][bo00]) = pack8(S0, S1);                                \
  *(bf16x8*)(&Bs[CUR][bo01]) = pack8(S2, S3);                                \
  *(bf16x8*)(&Bs[CUR][bo10]) = pack8(S4, S5);                                \
  *(bf16x8*)(&Bs[CUR][bo11]) = pack8(S6, S7);                                \
  asm volatile("s_waitcnt lgkmcnt(0)" ::: "memory");                         \
  __builtin_amdgcn_sched_barrier(0);                                         \
  if ((TI) < NT - 1) { asm volatile("s_waitcnt vmcnt(8)" ::: "memory"); }    \
  else { asm volatile("s_waitcnt vmcnt(0)" ::: "memory"); }                  \
  __builtin_amdgcn_s_barrier();                                              \
  __builtin_amdgcn_sched_barrier(0);                                         \
  if ((TI) + 1 < NT) stageA((CUR) ^ 1, ((TI) + 1) * BK);                     \
  __builtin_amdgcn_sched_barrier(0);                                         \
  if ((TI) + 2 < NT) { B_LOAD8(S0, S1, S2, S3, S4, S5, S6, S7, ((TI) + 2) * BK) } \
  __builtin_amdgcn_sched_barrier(0);                                         \
  mfma_tile(CUR);                                                            \
  __builtin_amdgcn_sched_barrier(0);

  // prologue: A(0) first, then B(0), B(1) — order matters for vmcnt counting
  float4 bA0, bA1, bA2, bA3, bA4, bA5, bA6, bA7;
  float4 bB0, bB1, bB2, bB3, bB4, bB5, bB6, bB7;
  stageA(0, 0);
  __builtin_amdgcn_sched_barrier(0);
  B_LOAD8(bA0, bA1, bA2, bA3, bA4, bA5, bA6, bA7, 0)
  B_LOAD8(bB0, bB1, bB2, bB3, bB4, bB5, bB6, bB7, BK)
  __builtin_amdgcn_sched_barrier(0);

  for (int tb = 0; tb < NT; tb += 2) {
    GEMM_STEP(tb, 0, bA0, bA1, bA2, bA3, bA4, bA5, bA6, bA7)
    GEMM_STEP(tb + 1, 1, bB0, bB1, bB2, bB3, bB4, bB5, bB6, bB7)
  }
#undef GEMM_STEP
#undef B_LOAD8

  const int lg = lane >> 4;
  if constexpr (MODE == 0) {
    if (n0 < 2048) {
#pragma unroll
      for (int m = 0; m < 4; ++m)
#pragma unroll
        for (int r = 0; r < 4; ++r) {
          const int row = wr + m * 16 + lg * 4 + r;
#pragma unroll
          for (int n = 0; n < 4; ++n) {
            const int col = n0 + wc + n * 16 + lr;
            out_bf[(size_t)(m0 + row) * 2048 + col] = (__bf16)acc[m][n][r];
          }
        }
    } else {
      // V half: write transposed [d_global = col-2048][s], 4 consecutive s packed
#pragma unroll
      for (int m = 0; m < 4; ++m) {
        const int sb = m0 + wr + m * 16 + lg * 4;
#pragma unroll
        for (int n = 0; n < 4; ++n) {
          const int cv = n0 + wc + n * 16 + lr - 2048;
          uint2 pk;
          unsigned short h0 = __builtin_bit_cast(unsigned short, (__bf16)acc[m][n][0]);
          unsigned short h1 = __builtin_bit_cast(unsigned short, (__bf16)acc[m][n][1]);
          unsigned short h2 = __builtin_bit_cast(unsigned short, (__bf16)acc[m][n][2]);
          unsigned short h3 = __builtin_bit_cast(unsigned short, (__bf16)acc[m][n][3]);
          pk.x = (unsigned)h0 | ((unsigned)h1 << 16);
          pk.y = (unsigned)h2 | ((unsigned)h3 << 16);
          *(uint2*)(out_vT + (size_t)cv * S_LEN + sb) = pk;
        }
      }
    }
  } else {
#pragma unroll
    for (int m = 0; m < 4; ++m) {
#pragma unroll
      for (int r = 0; r < 4; ++r) {
        const int row = wr + m * 16 + lg * 4 + r;
        const int pp = row_pair[row];
        if (pp < 0) continue;
        if constexpr (MODE == 1) {
#pragma unroll
          for (int n = 0; n < 4; ++n) {
            const int col = n0 + wc + n * 16 + lr;
            out_bf[(size_t)pp * QSZ + col] = (__bf16)acc[m][n][r];
          }
        } else {
          const float gt = gates[pp];
#pragma unroll
          for (int n = 0; n < 4; ++n) {
            const int col = n0 + wc + n * 16 + lr;
            out_f32[(size_t)pp * HSZ + col] = acc[m][n][r] * gt;
          }
        }
      }
    }
  }
}

// ---------------- RoPE + layout rearrange ----------------
__global__ __launch_bounds__(256) void rope_q_kernel(const __bf16* __restrict__ q_lin,
                                                     const float* __restrict__ cosb,
                                                     const float* __restrict__ sinb,
                                                     __bf16* __restrict__ q_attn) {
  const int idx = blockIdx.x * 4 + (threadIdx.x >> 6);
  const int lane = threadIdx.x & 63;
  const int s = idx >> 5;
  const int h = idx & 31;
  const int kvh = h >> 1, k = h & 1;
  const __bf16* src = q_lin + ((size_t)s * 2 + k) * QSZ + kvh * HD;
  float x1 = (float)src[lane];
  float x2 = (float)src[lane + 64];
  float c = cosb[s * 64 + lane], sn = sinb[s * 64 + lane];
  __bf16* dst = q_attn + ((size_t)h * S_LEN + s) * HD;
  dst[lane] = (__bf16)(x1 * c - x2 * sn);
  dst[lane + 64] = (__bf16)(x1 * sn + x2 * c);
}

__global__ __launch_bounds__(256) void rope_k_kernel(const __bf16* __restrict__ kv_lin,
                                                     const float* __restrict__ cosb,
                                                     const float* __restrict__ sinb,
                                                     __bf16* __restrict__ k_attn) {
  const int idx = blockIdx.x * 4 + (threadIdx.x >> 6);
  const int lane = threadIdx.x & 63;
  const int s = idx >> 4;
  const int gq = idx & 15;
  const __bf16* ksrc = kv_lin + (size_t)s * 2048 + gq * HD;
  float x1 = (float)ksrc[lane], x2 = (float)ksrc[lane + 64];
  float c = cosb[s * 64 + lane], sn = sinb[s * 64 + lane];
  __bf16* kd = k_attn + ((size_t)gq * S_LEN + s) * HD;
  kd[lane] = (__bf16)(x1 * c - x2 * sn);
  kd[lane + 64] = (__bf16)(x1 * sn + x2 * c);
}

// ---------------- flash attention v2 (causal, GQA 2:1) ----------------
__global__ __launch_bounds__(256, 2) void attn_kernel(const __bf16* __restrict__ q_attn,
                                                      const __bf16* __restrict__ k_attn,
                                                      const __bf16* __restrict__ vT,
                                                      __bf16* __restrict__ attn4) {
  __shared__ __attribute__((aligned(16))) __bf16 Ks[2][64 * 128];
  __shared__ __attribute__((aligned(16))) __bf16 Vs[2][128 * 64];
  const int h = blockIdx.x;
  const int by = (blockIdx.y < 8) ? blockIdx.y : 23 - blockIdx.y;  // pair heavy+light per CU
  const int s0 = by * 128;
  const int t = threadIdx.x;
  const int lane = t & 63;
  const int w = t >> 6;
  const int g = lane >> 4;
  const int lr = lane & 15;
  const int kvh = h >> 1;

  int koff[4], voff[4];
#pragma unroll
  for (int i = 0; i < 4; ++i) {
    const int c = t + i * 256;
    const int kvL = c >> 4, w16 = c & 15;
    koff[i] = kvL * HD + ((w16 ^ (kvL & 7)) * 8);
    const int d = c >> 3, w8 = c & 7;
    voff[i] = d * S_LEN + ((w8 ^ (d & 7)) * 8);
  }
  const __bf16* Kb = k_attn + (size_t)kvh * S_LEN * HD;
  const __bf16* Vb = vT + (size_t)kvh * HD * S_LEN;

  auto stage = [&](int buf, int kv0) {
#pragma unroll
    for (int i = 0; i < 4; ++i) {
      const int c = t + i * 256;
      gload_lds16(Kb + (size_t)kv0 * HD + koff[i], (char*)Ks[buf] + c * 16);
      gload_lds16(Vb + (size_t)kv0 + voff[i], (char*)Vs[buf] + c * 16);
    }
  };

  bf16x8 qf[2][4];
#pragma unroll
  for (int m = 0; m < 2; ++m) {
    const __bf16* qbase = q_attn + ((size_t)h * S_LEN + s0 + w * 32 + m * 16 + lr) * HD;
#pragma unroll
    for (int ds = 0; ds < 4; ++ds) qf[m][ds] = *(const bf16x8*)(qbase + ds * 32 + g * 8);
  }

  float m_run[2] = {-1e30f, -1e30f}, l_run[2] = {0.f, 0.f};
  f32x4 acc[2][8];
#pragma unroll
  for (int m = 0; m < 2; ++m)
#pragma unroll
    for (int dt = 0; dt < 8; ++dt) acc[m][dt] = (f32x4)0.f;

  const int xr = (lr & 7) << 4;
  const int nt = 2 * by + 2;
  stage(0, 0);
  for (int ti = 0; ti < nt; ++ti) {
    const int cur = ti & 1;
    const int kv0 = ti * 64;
    __syncthreads();
    if (ti + 1 < nt) stage(cur ^ 1, kv0 + 64);

    f32x4 sc[2][4];
#pragma unroll
    for (int m = 0; m < 2; ++m)
#pragma unroll
      for (int b = 0; b < 4; ++b) sc[m][b] = (f32x4)0.f;
#pragma unroll
    for (int b = 0; b < 4; ++b) {
#pragma unroll
      for (int ds = 0; ds < 4; ++ds) {
        const bf16x8 kf = *(const bf16x8*)((const char*)Ks[cur] +
            (b * 16 + lr) * 256 + ((ds * 64 + g * 16) ^ xr));
        sc[0][b] = __builtin_amdgcn_mfma_f32_16x16x32_bf16(kf, qf[0][ds], sc[0][b], 0, 0, 0);
        sc[1][b] = __builtin_amdgcn_mfma_f32_16x16x32_bf16(kf, qf[1][ds], sc[1][b], 0, 0, 0);
      }
    }

    bf16x8 paf[2][2];
#pragma unroll
    for (int m = 0; m < 2; ++m) {
      const int qrow = s0 + w * 32 + m * 16 + lr;
      float p[4][4];
      float tmax = -1e30f;
#pragma unroll
      for (int b = 0; b < 4; ++b)
#pragma unroll
        for (int r = 0; r < 4; ++r) {
          const int kv = kv0 + b * 16 + g * 4 + r;
          float v = sc[m][b][r] * 0.08838834764831845f;
          if (kv > qrow) v = -1e30f;
          p[b][r] = v;
          tmax = fmaxf(tmax, v);
        }
      tmax = fmaxf(tmax, __shfl_xor(tmax, 16));
      tmax = fmaxf(tmax, __shfl_xor(tmax, 32));
      const float m_new = fmaxf(m_run[m], tmax);
      const float alpha = __expf(m_run[m] - m_new);
      float lsum = 0.f;
#pragma unroll
      for (int b = 0; b < 4; ++b)
#pragma unroll
        for (int r = 0; r < 4; ++r) {
          p[b][r] = __expf(p[b][r] - m_new);
          lsum += p[b][r];
        }
      lsum += __shfl_xor(lsum, 16);
      lsum += __shfl_xor(lsum, 32);
      l_run[m] = l_run[m] * alpha + lsum;
      m_run[m] = m_new;

      float ar[4];
#pragma unroll
      for (int r = 0; r < 4; ++r) ar[r] = __shfl(alpha, g * 4 + r);
#pragma unroll
      for (int dt = 0; dt < 8; ++dt)
#pragma unroll
        for (int r = 0; r < 4; ++r) acc[m][dt][r] *= ar[r];

#pragma unroll
      for (int half = 0; half < 2; ++half) {
        bf16x8 af;
#pragma unroll
        for (int j = 0; j < 8; ++j) {
          const int srcl = lr + 16 * ((g & 1) * 2 + (j >> 2));
          const float va = __shfl(p[half * 2][j & 3], srcl);
          const float vb = __shfl(p[half * 2 + 1][j & 3], srcl);
          af[j] = (__bf16)((g >> 1) ? vb : va);
        }
        paf[m][half] = af;
      }
    }

#pragma unroll
    for (int dt = 0; dt < 8; ++dt) {
      const char* vrow = (const char*)Vs[cur] + (dt * 16 + lr) * 128;
      const bf16x8 v0 = *(const bf16x8*)(vrow + ((g * 16) ^ xr));
      const bf16x8 v1 = *(const bf16x8*)(vrow + ((64 + g * 16) ^ xr));
      acc[0][dt] = __builtin_amdgcn_mfma_f32_16x16x32_bf16(paf[0][0], v0, acc[0][dt], 0, 0, 0);
      acc[0][dt] = __builtin_amdgcn_mfma_f32_16x16x32_bf16(paf[0][1], v1, acc[0][dt], 0, 0, 0);
      acc[1][dt] = __builtin_amdgcn_mfma_f32_16x16x32_bf16(paf[1][0], v0, acc[1][dt], 0, 0, 0);
      acc[1][dt] = __builtin_amdgcn_mfma_f32_16x16x32_bf16(paf[1][1], v1, acc[1][dt], 0, 0, 0);
    }
  }

#pragma unroll
  for (int m = 0; m < 2; ++m) {
    const float li = 1.f / l_run[m];
    float linv[4];
#pragma unroll
    for (int r = 0; r < 4; ++r) linv[r] = __shfl(li, g * 4 + r);
#pragma unroll
    for (int dt = 0; dt < 8; ++dt)
#pragma unroll
      for (int r = 0; r < 4; ++r) {
        const int qg = s0 + w * 32 + m * 16 + g * 4 + r;
        attn4[((size_t)qg * 2 + (h & 1)) * QSZ + kvh * HD + dt * 16 + lr] =
            (__bf16)(acc[m][dt][r] * linv[r]);
      }
  }
}

// ---------------- final: out = bias + o_tmp[2s] + o_tmp[2s+1] ----------------
__global__ __launch_bounds__(256) void final_kernel(const float* __restrict__ o_tmp,
                                                    const float* __restrict__ bias,
                                                    float* __restrict__ out) {
  const size_t i = ((size_t)blockIdx.x * 256 + threadIdx.x) * 4;
  const int s = (int)(i >> 11);
  const int hcol = (int)(i & 2047);
  float4 a = *(const float4*)(o_tmp + ((size_t)s * 2) * HSZ + hcol);
  float4 b = *(const float4*)(o_tmp + ((size_t)s * 2 + 1) * HSZ + hcol);
  float4 bb = *(const float4*)(bias + hcol);
  float4 o;
  o.x = a.x + b.x + bb.x; o.y = a.y + b.y + bb.y;
  o.z = a.z + b.z + bb.z; o.w = a.w + b.w + bb.w;
  *(float4*)(out + i) = o;
}

extern "C" void kernel_launch(void* const* d_in, const int* in_sizes, int n_in,
                              void* d_out, int out_size, void* d_ws, size_t ws_size,
                              hipStream_t stream) {
  (void)in_sizes; (void)n_in; (void)out_size; (void)ws_size;
  const float* hs = (const float*)d_in[0];
  const float* cosb = (const float*)d_in[2];
  const float* sinb = (const float*)d_in[3];
  const float* rw = (const float*)d_in[4];
  const float* qw = (const float*)d_in[5];
  const float* ow = (const float*)d_in[6];
  const float* kvw = (const float*)d_in[7];
  const float* bias = (const float*)d_in[8];
  float* outp = (float*)d_out;

  char* base = (char*)d_ws;
  size_t off = 0;
  auto take = [&](size_t bytes) {
    char* r = base + off;
    off += (bytes + 255) & ~(size_t)255;
    return r;
  };
  __bf16* hid_bf  = (__bf16*)take((size_t)S_LEN * HSZ * 2);          // 8 MB
  __bf16* k_attn  = (__bf16*)take((size_t)NKVH * S_LEN * HD * 2);    // 8 MB
  __bf16* v_attnT = (__bf16*)take((size_t)NKVH * HD * S_LEN * 2);    // 8 MB, [d_global][s]
  char* bufA = take((size_t)S_LEN * 4096 * 2);                        // 16 MB: kv_lin(K), then attn4
  char* bufBC = take((size_t)S_LEN * TOPK * HSZ * 4);                 // 32 MB: q_lin|q_attn, then o_tmp
  int* sel = (int*)take((size_t)S_LEN * TOPK * 4);
  float* gates = (float*)take((size_t)S_LEN * TOPK * 4);
  int* pair_list = (int*)take((size_t)S_LEN * TOPK * 4);
  int* expert_off = (int*)take((size_t)(NE + 1) * 4);

  __bf16* kv_lin = (__bf16*)bufA;
  __bf16* attn4 = (__bf16*)bufA;
  __bf16* q_lin = (__bf16*)bufBC;
  __bf16* q_attn = (__bf16*)(bufBC + (size_t)16 * 1024 * 1024);
  float* o_tmp = (float*)bufBC;

  cast_kernel<<<1024, 256, 0, stream>>>(hs, hid_bf, (long)S_LEN * HSZ);
  router_kernel<<<S_LEN / 4, 256, 0, stream>>>(hs, rw, sel, gates);
  bucket_kernel<<<1, 256, 0, stream>>>(sel, pair_list, expert_off);
  gemm_kernel<0><<<dim3(4096 / BN, S_LEN / BM, 1), 256, 0, stream>>>(
      hid_bf, kvw, nullptr, nullptr, nullptr, kv_lin, v_attnT, nullptr);
  rope_k_kernel<<<S_LEN * NKVH / 4, 256, 0, stream>>>(kv_lin, cosb, sinb, k_attn);
  gemm_kernel<1><<<dim3(QSZ / BN, 32, NE), 256, 0, stream>>>(
      hid_bf, qw, pair_list, expert_off, nullptr, q_lin, nullptr, nullptr);
  rope_q_kernel<<<S_LEN * NQH / 4, 256, 0, stream>>>(q_lin, cosb, sinb, q_attn);
  attn_kernel<<<dim3(NQH, 16), 256, 0, stream>>>(q_attn, k_attn, v_attnT, attn4);
  gemm_kernel<2><<<dim3(HSZ / BN, 32, NE), 256, 0, stream>>>(
      attn4, ow, pair_list, expert_off, gates, nullptr, nullptr, o_tmp);
  final_kernel<<<(S_LEN * HSZ / 4) / 256, 256, 0, stream>>>(o_tmp, bias, outp);
}

// Round 9
// 407.337 us; speedup vs baseline: 1.4124x; 1.0451x over previous
//
#include <hip/hip_runtime.h>
#include <hip/hip_bf16.h>
#include <stdint.h>

#define S_LEN 2048
#define HSZ 2048
#define NE 8
#define TOPK 2
#define NKVH 16
#define HD 128
#define NQH 32
#define QSZ 2048

typedef __attribute__((ext_vector_type(8))) __bf16 bf16x8;
typedef __attribute__((ext_vector_type(4))) float f32x4;

#define BM 128
#define BN 128
#define BK 64

__device__ __forceinline__ void gload_lds16(const void* g, void* l) {
  __builtin_amdgcn_global_load_lds((__attribute__((address_space(1))) void*)g,
                                   (__attribute__((address_space(3))) void*)l, 16, 0, 0);
}

__device__ __forceinline__ bf16x8 pack8(float4 a, float4 b) {
  bf16x8 r;
  r[0] = (__bf16)a.x; r[1] = (__bf16)a.y; r[2] = (__bf16)a.z; r[3] = (__bf16)a.w;
  r[4] = (__bf16)b.x; r[5] = (__bf16)b.y; r[6] = (__bf16)b.z; r[7] = (__bf16)b.w;
  return r;
}

// ---------------- cast f32 -> bf16 (hidden states only) ----------------
__global__ __launch_bounds__(256) void cast_kernel(const float* __restrict__ src,
                                                   __bf16* __restrict__ dst, long n) {
  long i0 = ((long)blockIdx.x * 256 + threadIdx.x) * 4;
  long stride = (long)gridDim.x * 256 * 4;
  for (long i = i0; i < n; i += stride) {
    float4 v = *(const float4*)(src + i);
    unsigned short a = __builtin_bit_cast(unsigned short, (__bf16)v.x);
    unsigned short b = __builtin_bit_cast(unsigned short, (__bf16)v.y);
    unsigned short c = __builtin_bit_cast(unsigned short, (__bf16)v.z);
    unsigned short d = __builtin_bit_cast(unsigned short, (__bf16)v.w);
    uint2 o;
    o.x = (unsigned)a | ((unsigned)b << 16);
    o.y = (unsigned)c | ((unsigned)d << 16);
    *(uint2*)(dst + i) = o;
  }
}

// ---------------- router: logits + top2 + gates ----------------
__global__ __launch_bounds__(256) void router_kernel(const float* __restrict__ hs,
                                                     const float* __restrict__ rw,
                                                     int* __restrict__ sel,
                                                     float* __restrict__ gates) {
  const int s = blockIdx.x * 4 + (threadIdx.x >> 6);
  const int lane = threadIdx.x & 63;
  const float* row = hs + (size_t)s * HSZ;
  float acc[NE];
#pragma unroll
  for (int e = 0; e < NE; ++e) acc[e] = 0.f;
  for (int j = lane; j < HSZ; j += 64) {
    float x = row[j];
#pragma unroll
    for (int e = 0; e < NE; ++e) acc[e] += x * rw[e * HSZ + j];
  }
#pragma unroll
  for (int e = 0; e < NE; ++e) {
#pragma unroll
    for (int off = 32; off > 0; off >>= 1) acc[e] += __shfl_xor(acc[e], off);
  }
  if (lane == 0) {
    int i0 = 0; float v0 = acc[0];
#pragma unroll
    for (int e = 1; e < NE; ++e) if (acc[e] > v0) { v0 = acc[e]; i0 = e; }
    int i1 = -1; float v1 = -1e30f;
#pragma unroll
    for (int e = 0; e < NE; ++e) if (e != i0 && acc[e] > v1) { v1 = acc[e]; i1 = e; }
    float ge = __expf(v1 - v0);
    float den = 1.f + ge;
    sel[s * 2] = i0; sel[s * 2 + 1] = i1;
    gates[s * 2] = 1.f / den; gates[s * 2 + 1] = ge / den;
  }
}

// ---------------- bucket (token,slot) pairs by expert ----------------
__global__ void bucket_kernel(const int* __restrict__ sel, int* __restrict__ pair_list,
                              int* __restrict__ expert_off) {
  __shared__ int cnt[NE], base[NE];
  const int t = threadIdx.x;
  if (t < NE) cnt[t] = 0;
  __syncthreads();
  for (int p2 = t; p2 < S_LEN * TOPK; p2 += 256) atomicAdd(&cnt[sel[p2]], 1);
  __syncthreads();
  if (t == 0) {
    int run = 0;
#pragma unroll
    for (int e = 0; e < NE; ++e) { base[e] = run; expert_off[e] = run; run += cnt[e]; }
    expert_off[NE] = run;
  }
  __syncthreads();
  for (int p2 = t; p2 < S_LEN * TOPK; p2 += 256) {
    int pos = atomicAdd(&base[sel[p2]], 1);
    pair_list[pos] = p2;
  }
}

// ---------------- GEMM v7: 128^2 tile, 8 waves (wave-tile 32x64), 2 blk/CU ----
// Same R8 counted schedule; 512 threads double waves/SIMD (2->4) to hide the
// per-wave staging latency under more co-resident MFMA work.
template <int MODE>
__global__ __launch_bounds__(512, 4) void gemm_kernel(const __bf16* __restrict__ A_src,
                                                      const float* __restrict__ B_src,
                                                      const int* __restrict__ pair_list,
                                                      const int* __restrict__ expert_off,
                                                      const float* __restrict__ gates,
                                                      __bf16* __restrict__ out_bf,
                                                      __bf16* __restrict__ out_vT,
                                                      float* __restrict__ out_f32) {
  constexpr int KD = 2048;
  constexpr int NT = KD / BK;  // 32 (even)
  const int n0 = blockIdx.x * BN;
  const int m0 = blockIdx.y * BM;
  const int e = blockIdx.z;
  int start = 0, cntv = S_LEN;
  if constexpr (MODE != 0) {
    start = expert_off[e];
    cntv = expert_off[e + 1] - start;
    if (m0 >= cntv) return;
  }
  const float* Bb = B_src + (size_t)e * QSZ * HSZ;
  __shared__ __attribute__((aligned(16))) __bf16 As[2][BM * BK];
  __shared__ __attribute__((aligned(16))) __bf16 Bs[2][BN * BK];
  __shared__ const __bf16* a_rows[BM];
  __shared__ int row_pair[BM];
  const int t = threadIdx.x;
  if (t < BM) {
    if constexpr (MODE == 0) {
      a_rows[t] = A_src + (size_t)(m0 + t) * KD;
      row_pair[t] = 0;
    } else {
      int idx = m0 + t;
      bool valid = idx < cntv;
      int pp = pair_list[start + (valid ? idx : 0)];
      row_pair[t] = valid ? pp : -1;
      size_t arow = (MODE == 1) ? (size_t)(pp >> 1) : (size_t)pp;
      a_rows[t] = A_src + arow * (size_t)KD;
    }
  }
  __syncthreads();

  const int lane = t & 63, w = t >> 6;        // 8 waves
  const int wr = (w >> 1) * 32, wc = (w & 1) * 64;  // 4M x 2N wave grid
  const int lr = lane & 15, g = lane >> 4;
  const int xa = lr & 7;  // read-side swizzle key

  // A staging: 1024 16B-chunks, 2/thread; linear LDS dest, inverse-swizzled src.
  const __bf16* a_srow[2];
  int a_soff[2];
#pragma unroll
  for (int i = 0; i < 2; ++i) {
    const int c = t + i * 512;
    const int row = c >> 3, win = c & 7;
    a_srow[i] = a_rows[row];
    a_soff[i] = (win ^ (row & 7)) * 8;
  }

  // B staging: thread t -> row t>>2, f32 elems [(t&3)*16,+16); swizzled ds_write.
  const int brow = t >> 2;
  const int bq = t & 3;
  const float* bp0 = Bb + (size_t)(n0 + brow) * KD + bq * 16;
  const int c0 = (2 * bq) ^ (brow & 7);
  const int c1 = (2 * bq + 1) ^ (brow & 7);
  const int bo0 = brow * BK + c0 * 8, bo1 = brow * BK + c1 * 8;

  f32x4 acc[2][4];
#pragma unroll
  for (int m = 0; m < 2; ++m)
#pragma unroll
    for (int n = 0; n < 4; ++n) acc[m][n] = (f32x4)0.f;

  auto stageA = [&](int dstbuf, int k0) {
#pragma unroll
    for (int i = 0; i < 2; ++i)
      gload_lds16(a_srow[i] + k0 + a_soff[i], (char*)As[dstbuf] + (t + i * 512) * 16);
  };
  auto mfma_tile = [&](int cur) {
#pragma unroll
    for (int kk = 0; kk < BK; kk += 32) {
      bf16x8 af[2], bfv[4];
#pragma unroll
      for (int m = 0; m < 2; ++m)
        af[m] = *(const bf16x8*)(&As[cur][(wr + m * 16 + lr) * BK + (((kk >> 3) + g) ^ xa) * 8]);
#pragma unroll
      for (int n = 0; n < 4; ++n)
        bfv[n] = *(const bf16x8*)(&Bs[cur][(wc + n * 16 + lr) * BK + (((kk >> 3) + g) ^ xa) * 8]);
#pragma unroll
      for (int m = 0; m < 2; ++m)
#pragma unroll
        for (int n = 0; n < 4; ++n)
          acc[m][n] = __builtin_amdgcn_mfma_f32_16x16x32_bf16(af[m], bfv[n], acc[m][n], 0, 0, 0);
    }
  };

#define B_LOAD4(S0, S1, S2, S3, KB)                                          \
  S0 = *(const float4*)(bp0 + (KB));     S1 = *(const float4*)(bp0 + (KB) + 4); \
  S2 = *(const float4*)(bp0 + (KB) + 8); S3 = *(const float4*)(bp0 + (KB) + 12);

// iter: pack -> lgkm -> vmcnt(4) -> barrier -> stageA(ti+1) -> B_LOAD(ti+2) -> MFMA
#define GEMM_STEP(TI, CUR, S0, S1, S2, S3)                                   \
  *(bf16x8*)(&Bs[CUR][bo0]) = pack8(S0, S1);                                 \
  *(bf16x8*)(&Bs[CUR][bo1]) = pack8(S2, S3);                                 \
  asm volatile("s_waitcnt lgkmcnt(0)" ::: "memory");                         \
  __builtin_amdgcn_sched_barrier(0);                                         \
  if ((TI) < NT - 1) { asm volatile("s_waitcnt vmcnt(4)" ::: "memory"); }    \
  else { asm volatile("s_waitcnt vmcnt(0)" ::: "memory"); }                  \
  __builtin_amdgcn_s_barrier();                                              \
  __builtin_amdgcn_sched_barrier(0);                                         \
  if ((TI) + 1 < NT) stageA((CUR) ^ 1, ((TI) + 1) * BK);                     \
  __builtin_amdgcn_sched_barrier(0);                                         \
  if ((TI) + 2 < NT) { B_LOAD4(S0, S1, S2, S3, ((TI) + 2) * BK) }            \
  __builtin_amdgcn_sched_barrier(0);                                         \
  mfma_tile(CUR);                                                            \
  __builtin_amdgcn_sched_barrier(0);

  // prologue: A(0) first, then B(0), B(1) — order matters for vmcnt counting
  float4 bA0, bA1, bA2, bA3;
  float4 bB0, bB1, bB2, bB3;
  stageA(0, 0);
  __builtin_amdgcn_sched_barrier(0);
  B_LOAD4(bA0, bA1, bA2, bA3, 0)
  B_LOAD4(bB0, bB1, bB2, bB3, BK)
  __builtin_amdgcn_sched_barrier(0);

  for (int tb = 0; tb < NT; tb += 2) {
    GEMM_STEP(tb, 0, bA0, bA1, bA2, bA3)
    GEMM_STEP(tb + 1, 1, bB0, bB1, bB2, bB3)
  }
#undef GEMM_STEP
#undef B_LOAD4

  const int lg = lane >> 4;
  if constexpr (MODE == 0) {
    if (n0 < 2048) {
#pragma unroll
      for (int m = 0; m < 2; ++m)
#pragma unroll
        for (int r = 0; r < 4; ++r) {
          const int row = wr + m * 16 + lg * 4 + r;
#pragma unroll
          for (int n = 0; n < 4; ++n) {
            const int col = n0 + wc + n * 16 + lr;
            out_bf[(size_t)(m0 + row) * 2048 + col] = (__bf16)acc[m][n][r];
          }
        }
    } else {
      // V half: write transposed [d_global = col-2048][s], 4 consecutive s packed
#pragma unroll
      for (int m = 0; m < 2; ++m) {
        const int sb = m0 + wr + m * 16 + lg * 4;
#pragma unroll
        for (int n = 0; n < 4; ++n) {
          const int cv = n0 + wc + n * 16 + lr - 2048;
          uint2 pk;
          unsigned short h0 = __builtin_bit_cast(unsigned short, (__bf16)acc[m][n][0]);
          unsigned short h1 = __builtin_bit_cast(unsigned short, (__bf16)acc[m][n][1]);
          unsigned short h2 = __builtin_bit_cast(unsigned short, (__bf16)acc[m][n][2]);
          unsigned short h3 = __builtin_bit_cast(unsigned short, (__bf16)acc[m][n][3]);
          pk.x = (unsigned)h0 | ((unsigned)h1 << 16);
          pk.y = (unsigned)h2 | ((unsigned)h3 << 16);
          *(uint2*)(out_vT + (size_t)cv * S_LEN + sb) = pk;
        }
      }
    }
  } else {
#pragma unroll
    for (int m = 0; m < 2; ++m) {
#pragma unroll
      for (int r = 0; r < 4; ++r) {
        const int row = wr + m * 16 + lg * 4 + r;
        const int pp = row_pair[row];
        if (pp < 0) continue;
        if constexpr (MODE == 1) {
#pragma unroll
          for (int n = 0; n < 4; ++n) {
            const int col = n0 + wc + n * 16 + lr;
            out_bf[(size_t)pp * QSZ + col] = (__bf16)acc[m][n][r];
          }
        } else {
          const float gt = gates[pp];
#pragma unroll
          for (int n = 0; n < 4; ++n) {
            const int col = n0 + wc + n * 16 + lr;
            out_f32[(size_t)pp * HSZ + col] = acc[m][n][r] * gt;
          }
        }
      }
    }
  }
}

// ---------------- RoPE + layout rearrange ----------------
__global__ __launch_bounds__(256) void rope_q_kernel(const __bf16* __restrict__ q_lin,
                                                     const float* __restrict__ cosb,
                                                     const float* __restrict__ sinb,
                                                     __bf16* __restrict__ q_attn) {
  const int idx = blockIdx.x * 4 + (threadIdx.x >> 6);
  const int lane = threadIdx.x & 63;
  const int s = idx >> 5;
  const int h = idx & 31;
  const int kvh = h >> 1, k = h & 1;
  const __bf16* src = q_lin + ((size_t)s * 2 + k) * QSZ + kvh * HD;
  float x1 = (float)src[lane];
  float x2 = (float)src[lane + 64];
  float c = cosb[s * 64 + lane], sn = sinb[s * 64 + lane];
  __bf16* dst = q_attn + ((size_t)h * S_LEN + s) * HD;
  dst[lane] = (__bf16)(x1 * c - x2 * sn);
  dst[lane + 64] = (__bf16)(x1 * sn + x2 * c);
}

__global__ __launch_bounds__(256) void rope_k_kernel(const __bf16* __restrict__ kv_lin,
                                                     const float* __restrict__ cosb,
                                                     const float* __restrict__ sinb,
                                                     __bf16* __restrict__ k_attn) {
  const int idx = blockIdx.x * 4 + (threadIdx.x >> 6);
  const int lane = threadIdx.x & 63;
  const int s = idx >> 4;
  const int gq = idx & 15;
  const __bf16* ksrc = kv_lin + (size_t)s * 2048 + gq * HD;
  float x1 = (float)ksrc[lane], x2 = (float)ksrc[lane + 64];
  float c = cosb[s * 64 + lane], sn = sinb[s * 64 + lane];
  __bf16* kd = k_attn + ((size_t)gq * S_LEN + s) * HD;
  kd[lane] = (__bf16)(x1 * c - x2 * sn);
  kd[lane + 64] = (__bf16)(x1 * sn + x2 * c);
}

// ---------------- flash attention v2 (causal, GQA 2:1) ----------------
__global__ __launch_bounds__(256, 2) void attn_kernel(const __bf16* __restrict__ q_attn,
                                                      const __bf16* __restrict__ k_attn,
                                                      const __bf16* __restrict__ vT,
                                                      __bf16* __restrict__ attn4) {
  __shared__ __attribute__((aligned(16))) __bf16 Ks[2][64 * 128];
  __shared__ __attribute__((aligned(16))) __bf16 Vs[2][128 * 64];
  const int h = blockIdx.x;
  const int by = (blockIdx.y < 8) ? blockIdx.y : 23 - blockIdx.y;  // pair heavy+light per CU
  const int s0 = by * 128;
  const int t = threadIdx.x;
  const int lane = t & 63;
  const int w = t >> 6;
  const int g = lane >> 4;
  const int lr = lane & 15;
  const int kvh = h >> 1;

  int koff[4], voff[4];
#pragma unroll
  for (int i = 0; i < 4; ++i) {
    const int c = t + i * 256;
    const int kvL = c >> 4, w16 = c & 15;
    koff[i] = kvL * HD + ((w16 ^ (kvL & 7)) * 8);
    const int d = c >> 3, w8 = c & 7;
    voff[i] = d * S_LEN + ((w8 ^ (d & 7)) * 8);
  }
  const __bf16* Kb = k_attn + (size_t)kvh * S_LEN * HD;
  const __bf16* Vb = vT + (size_t)kvh * HD * S_LEN;

  auto stage = [&](int buf, int kv0) {
#pragma unroll
    for (int i = 0; i < 4; ++i) {
      const int c = t + i * 256;
      gload_lds16(Kb + (size_t)kv0 * HD + koff[i], (char*)Ks[buf] + c * 16);
      gload_lds16(Vb + (size_t)kv0 + voff[i], (char*)Vs[buf] + c * 16);
    }
  };

  bf16x8 qf[2][4];
#pragma unroll
  for (int m = 0; m < 2; ++m) {
    const __bf16* qbase = q_attn + ((size_t)h * S_LEN + s0 + w * 32 + m * 16 + lr) * HD;
#pragma unroll
    for (int ds = 0; ds < 4; ++ds) qf[m][ds] = *(const bf16x8*)(qbase + ds * 32 + g * 8);
  }

  float m_run[2] = {-1e30f, -1e30f}, l_run[2] = {0.f, 0.f};
  f32x4 acc[2][8];
#pragma unroll
  for (int m = 0; m < 2; ++m)
#pragma unroll
    for (int dt = 0; dt < 8; ++dt) acc[m][dt] = (f32x4)0.f;

  const int xr = (lr & 7) << 4;
  const int nt = 2 * by + 2;
  stage(0, 0);
  for (int ti = 0; ti < nt; ++ti) {
    const int cur = ti & 1;
    const int kv0 = ti * 64;
    __syncthreads();
    if (ti + 1 < nt) stage(cur ^ 1, kv0 + 64);

    f32x4 sc[2][4];
#pragma unroll
    for (int m = 0; m < 2; ++m)
#pragma unroll
      for (int b = 0; b < 4; ++b) sc[m][b] = (f32x4)0.f;
#pragma unroll
    for (int b = 0; b < 4; ++b) {
#pragma unroll
      for (int ds = 0; ds < 4; ++ds) {
        const bf16x8 kf = *(const bf16x8*)((const char*)Ks[cur] +
            (b * 16 + lr) * 256 + ((ds * 64 + g * 16) ^ xr));
        sc[0][b] = __builtin_amdgcn_mfma_f32_16x16x32_bf16(kf, qf[0][ds], sc[0][b], 0, 0, 0);
        sc[1][b] = __builtin_amdgcn_mfma_f32_16x16x32_bf16(kf, qf[1][ds], sc[1][b], 0, 0, 0);
      }
    }

    bf16x8 paf[2][2];
#pragma unroll
    for (int m = 0; m < 2; ++m) {
      const int qrow = s0 + w * 32 + m * 16 + lr;
      float p[4][4];
      float tmax = -1e30f;
#pragma unroll
      for (int b = 0; b < 4; ++b)
#pragma unroll
        for (int r = 0; r < 4; ++r) {
          const int kv = kv0 + b * 16 + g * 4 + r;
          float v = sc[m][b][r] * 0.08838834764831845f;
          if (kv > qrow) v = -1e30f;
          p[b][r] = v;
          tmax = fmaxf(tmax, v);
        }
      tmax = fmaxf(tmax, __shfl_xor(tmax, 16));
      tmax = fmaxf(tmax, __shfl_xor(tmax, 32));
      const float m_new = fmaxf(m_run[m], tmax);
      const float alpha = __expf(m_run[m] - m_new);
      float lsum = 0.f;
#pragma unroll
      for (int b = 0; b < 4; ++b)
#pragma unroll
        for (int r = 0; r < 4; ++r) {
          p[b][r] = __expf(p[b][r] - m_new);
          lsum += p[b][r];
        }
      lsum += __shfl_xor(lsum, 16);
      lsum += __shfl_xor(lsum, 32);
      l_run[m] = l_run[m] * alpha + lsum;
      m_run[m] = m_new;

      float ar[4];
#pragma unroll
      for (int r = 0; r < 4; ++r) ar[r] = __shfl(alpha, g * 4 + r);
#pragma unroll
      for (int dt = 0; dt < 8; ++dt)
#pragma unroll
        for (int r = 0; r < 4; ++r) acc[m][dt][r] *= ar[r];

#pragma unroll
      for (int half = 0; half < 2; ++half) {
        bf16x8 af;
#pragma unroll
        for (int j = 0; j < 8; ++j) {
          const int srcl = lr + 16 * ((g & 1) * 2 + (j >> 2));
          const float va = __shfl(p[half * 2][j & 3], srcl);
          const float vb = __shfl(p[half * 2 + 1][j & 3], srcl);
          af[j] = (__bf16)((g >> 1) ? vb : va);
        }
        paf[m][half] = af;
      }
    }

#pragma unroll
    for (int dt = 0; dt < 8; ++dt) {
      const char* vrow = (const char*)Vs[cur] + (dt * 16 + lr) * 128;
      const bf16x8 v0 = *(const bf16x8*)(vrow + ((g * 16) ^ xr));
      const bf16x8 v1 = *(const bf16x8*)(vrow + ((64 + g * 16) ^ xr));
      acc[0][dt] = __builtin_amdgcn_mfma_f32_16x16x32_bf16(paf[0][0], v0, acc[0][dt], 0, 0, 0);
      acc[0][dt] = __builtin_amdgcn_mfma_f32_16x16x32_bf16(paf[0][1], v1, acc[0][dt], 0, 0, 0);
      acc[1][dt] = __builtin_amdgcn_mfma_f32_16x16x32_bf16(paf[1][0], v0, acc[1][dt], 0, 0, 0);
      acc[1][dt] = __builtin_amdgcn_mfma_f32_16x16x32_bf16(paf[1][1], v1, acc[1][dt], 0, 0, 0);
    }
  }

#pragma unroll
  for (int m = 0; m < 2; ++m) {
    const float li = 1.f / l_run[m];
    float linv[4];
#pragma unroll
    for (int r = 0; r < 4; ++r) linv[r] = __shfl(li, g * 4 + r);
#pragma unroll
    for (int dt = 0; dt < 8; ++dt)
#pragma unroll
      for (int r = 0; r < 4; ++r) {
        const int qg = s0 + w * 32 + m * 16 + g * 4 + r;
        attn4[((size_t)qg * 2 + (h & 1)) * QSZ + kvh * HD + dt * 16 + lr] =
            (__bf16)(acc[m][dt][r] * linv[r]);
      }
  }
}

// ---------------- final: out = bias + o_tmp[2s] + o_tmp[2s+1] ----------------
__global__ __launch_bounds__(256) void final_kernel(const float* __restrict__ o_tmp,
                                                    const float* __restrict__ bias,
                                                    float* __restrict__ out) {
  const size_t i = ((size_t)blockIdx.x * 256 + threadIdx.x) * 4;
  const int s = (int)(i >> 11);
  const int hcol = (int)(i & 2047);
  float4 a = *(const float4*)(o_tmp + ((size_t)s * 2) * HSZ + hcol);
  float4 b = *(const float4*)(o_tmp + ((size_t)s * 2 + 1) * HSZ + hcol);
  float4 bb = *(const float4*)(bias + hcol);
  float4 o;
  o.x = a.x + b.x + bb.x; o.y = a.y + b.y + bb.y;
  o.z = a.z + b.z + bb.z; o.w = a.w + b.w + bb.w;
  *(float4*)(out + i) = o;
}

extern "C" void kernel_launch(void* const* d_in, const int* in_sizes, int n_in,
                              void* d_out, int out_size, void* d_ws, size_t ws_size,
                              hipStream_t stream) {
  (void)in_sizes; (void)n_in; (void)out_size; (void)ws_size;
  const float* hs = (const float*)d_in[0];
  const float* cosb = (const float*)d_in[2];
  const float* sinb = (const float*)d_in[3];
  const float* rw = (const float*)d_in[4];
  const float* qw = (const float*)d_in[5];
  const float* ow = (const float*)d_in[6];
  const float* kvw = (const float*)d_in[7];
  const float* bias = (const float*)d_in[8];
  float* outp = (float*)d_out;

  char* base = (char*)d_ws;
  size_t off = 0;
  auto take = [&](size_t bytes) {
    char* r = base + off;
    off += (bytes + 255) & ~(size_t)255;
    return r;
  };
  __bf16* hid_bf  = (__bf16*)take((size_t)S_LEN * HSZ * 2);          // 8 MB
  __bf16* k_attn  = (__bf16*)take((size_t)NKVH * S_LEN * HD * 2);    // 8 MB
  __bf16* v_attnT = (__bf16*)take((size_t)NKVH * HD * S_LEN * 2);    // 8 MB, [d_global][s]
  char* bufA = take((size_t)S_LEN * 4096 * 2);                        // 16 MB: kv_lin(K), then attn4
  char* bufBC = take((size_t)S_LEN * TOPK * HSZ * 4);                 // 32 MB: q_lin|q_attn, then o_tmp
  int* sel = (int*)take((size_t)S_LEN * TOPK * 4);
  float* gates = (float*)take((size_t)S_LEN * TOPK * 4);
  int* pair_list = (int*)take((size_t)S_LEN * TOPK * 4);
  int* expert_off = (int*)take((size_t)(NE + 1) * 4);

  __bf16* kv_lin = (__bf16*)bufA;
  __bf16* attn4 = (__bf16*)bufA;
  __bf16* q_lin = (__bf16*)bufBC;
  __bf16* q_attn = (__bf16*)(bufBC + (size_t)16 * 1024 * 1024);
  float* o_tmp = (float*)bufBC;

  cast_kernel<<<1024, 256, 0, stream>>>(hs, hid_bf, (long)S_LEN * HSZ);
  router_kernel<<<S_LEN / 4, 256, 0, stream>>>(hs, rw, sel, gates);
  bucket_kernel<<<1, 256, 0, stream>>>(sel, pair_list, expert_off);
  gemm_kernel<0><<<dim3(4096 / BN, S_LEN / BM, 1), 512, 0, stream>>>(
      hid_bf, kvw, nullptr, nullptr, nullptr, kv_lin, v_attnT, nullptr);
  rope_k_kernel<<<S_LEN * NKVH / 4, 256, 0, stream>>>(kv_lin, cosb, sinb, k_attn);
  gemm_kernel<1><<<dim3(QSZ / BN, 8, NE), 512, 0, stream>>>(
      hid_bf, qw, pair_list, expert_off, nullptr, q_lin, nullptr, nullptr);
  rope_q_kernel<<<S_LEN * NQH / 4, 256, 0, stream>>>(q_lin, cosb, sinb, q_attn);
  attn_kernel<<<dim3(NQH, 16), 256, 0, stream>>>(q_attn, k_attn, v_attnT, attn4);
  gemm_kernel<2><<<dim3(HSZ / BN, 8, NE), 512, 0, stream>>>(
      attn4, ow, pair_list, expert_off, gates, nullptr, nullptr, o_tmp);
  final_kernel<<<(S_LEN * HSZ / 4) / 256, 256, 0, stream>>>(o_tmp, bias, outp);
}